// Round 6
// baseline (134.165 us; speedup 1.0000x reference)
//
#include <hip/hip_runtime.h>
#include <math.h>

// MHAttention: BS=8, D=256, L=1024, H=8, DK=32
// Round 6 = Round 5 structure + scratch-aliasing fix. R5's NaN: wqt scratch
// (16896..20992) overlapped qsb (19456..), and rr=1 of the q-projection read
// wqt after rr=0's qsb writes clobbered it. Scratch now lives in ks (wqt)
// and pbf (qtmp) regions, which are provably dead until after the prologue.
// 128-row attn blocks (512 blocks), XCD swizzle bid=strip*64+bh, wave owns
// 32 rows (2 rt subtiles), 52 KB LDS -> 2 blocks/CU.

constexpr int cD  = 256;
constexpr int cL  = 1024;
constexpr int cH  = 8;
constexpr int cDK = 32;

typedef _Float16 f16;
typedef __attribute__((ext_vector_type(8))) _Float16 h8;   // 8 f16 = 4 VGPRs
typedef __attribute__((ext_vector_type(4))) _Float16 h4;   // 8 B
typedef __attribute__((ext_vector_type(4))) float f4v;     // MFMA C/D

// ---------------------------------------------------------------------------
// Kernel 1: K -> masked fp16 [b][h][l][c] (A-frag staging layout);
// V -> fp16 [b][h][c][l]. grid 1024 = (b:8, h:8, lt:16 of 64 l), block 256.
// ---------------------------------------------------------------------------
__global__ __launch_bounds__(256, 4) void proj_kv_kernel(
    const float* __restrict__ keys, const float* __restrict__ values,
    const float* __restrict__ mask, const float* __restrict__ Wk,
    const float* __restrict__ Wv, f16* __restrict__ kp_h,
    f16* __restrict__ vp_h)
{
    __shared__ __align__(16) float xs[32][68];
    __shared__ __align__(16) float wT[32][36];
    __shared__ float msl[64];

    const int t   = threadIdx.x;
    const int bid = blockIdx.x;
    const int lt  = bid & 15;
    const int h   = (bid >> 4) & 7;
    const int b   = bid >> 7;
    const int l0  = lt * 64;

    if (t < 64) msl[t] = mask[b * cL + l0 + t];

    // ---------------- K pass ----------------
    for (int idx = t; idx < 512; idx += 256) {
        int j = idx >> 4, l4 = (idx & 15) * 4;
        *reinterpret_cast<float4*>(&xs[j][l4]) =
            *reinterpret_cast<const float4*>(&keys[(b * cD + h * cDK + j) * cL + l0 + l4]);
    }
    for (int idx = t; idx < 1024; idx += 256) {
        int c = idx >> 5, j = idx & 31;
        wT[j][c] = Wk[(h * cDK + c) * cDK + j];
    }
    __syncthreads();
    {
        // lane map: ig = t&3 fast -> K stores are 16B x 64 lanes contiguous
        const int l = t >> 2, ig = t & 3;
        float acc[8] = {0, 0, 0, 0, 0, 0, 0, 0};
        #pragma unroll
        for (int j = 0; j < 32; ++j) {
            float xv = xs[j][l];                     // 4-lane broadcast
            float4 w0 = *reinterpret_cast<const float4*>(&wT[j][ig * 8]);
            float4 w1 = *reinterpret_cast<const float4*>(&wT[j][ig * 8 + 4]);
            acc[0] += w0.x * xv; acc[1] += w0.y * xv;
            acc[2] += w0.z * xv; acc[3] += w0.w * xv;
            acc[4] += w1.x * xv; acc[5] += w1.y * xv;
            acc[6] += w1.z * xv; acc[7] += w1.w * xv;
        }
        float mk = msl[l];
        h8 hv;
        #pragma unroll
        for (int i = 0; i < 8; ++i) hv[i] = (f16)(acc[i] * mk);
        size_t off = (((size_t)(b * cH + h)) * cL + l0 + l) * cDK + ig * 8;
        *reinterpret_cast<h8*>(&kp_h[off]) = hv;
    }
    __syncthreads();

    // ---------------- V pass ----------------
    for (int idx = t; idx < 512; idx += 256) {
        int j = idx >> 4, l4 = (idx & 15) * 4;
        *reinterpret_cast<float4*>(&xs[j][l4]) =
            *reinterpret_cast<const float4*>(&values[(b * cD + h * cDK + j) * cL + l0 + l4]);
    }
    for (int idx = t; idx < 1024; idx += 256) {
        int c = idx >> 5, j = idx & 31;
        wT[j][c] = Wv[(h * cDK + c) * cDK + j];
    }
    __syncthreads();
    {
        const int l4 = (t & 15) * 4;
        const int c0 = (t >> 4) * 2;
        float a0[4] = {0, 0, 0, 0}, a1[4] = {0, 0, 0, 0};
        #pragma unroll
        for (int j = 0; j < 32; ++j) {
            float4 xv = *reinterpret_cast<const float4*>(&xs[j][l4]);
            float w0 = wT[j][c0], w1 = wT[j][c0 + 1];
            a0[0] += w0 * xv.x; a0[1] += w0 * xv.y; a0[2] += w0 * xv.z; a0[3] += w0 * xv.w;
            a1[0] += w1 * xv.x; a1[1] += w1 * xv.y; a1[2] += w1 * xv.z; a1[3] += w1 * xv.w;
        }
        size_t base = ((size_t)(b * cH + h)) * cDK;
        h4 v0, v1;
        #pragma unroll
        for (int i = 0; i < 4; ++i) { v0[i] = (f16)a0[i]; v1[i] = (f16)a1[i]; }
        *reinterpret_cast<h4*>(&vp_h[(base + c0) * cL + l0 + l4])     = v0;
        *reinterpret_cast<h4*>(&vp_h[(base + c0 + 1) * cL + l0 + l4]) = v1;
    }
}

// ---------------------------------------------------------------------------
// Kernel 2: fused attention, fp16 MFMA. Block = (b, h, 128-row strip), 4
// waves; wave w owns rows w*32 .. w*32+32 as two 16-row subtiles (rt=0,1).
// grid 512: bid = strip*64 + bh (all strips of one (b,h) on one XCD).
// ---------------------------------------------------------------------------
__global__ __launch_bounds__(256, 2) void attn_kernel(
    const float* __restrict__ queries, const float* __restrict__ mask,
    const float* __restrict__ Wq, const f16* __restrict__ kp_h,
    const f16* __restrict__ vp_h, f16* __restrict__ val_h)
{
    __shared__ __align__(16) char smem[52224];
    f16*   ks    = (f16*)smem;             // [2][64e][40]  10240 B, rows 80 B
    f16*   vsb   = (f16*)(smem + 10240);   // [2][32c][72]   9216 B, rows 144 B
    f16*   qsb   = (f16*)(smem + 19456);   // [128r][40]    10240 B
    f16*   pbf   = (f16*)(smem + 29696);   // [128r][72]    18432 B, rows 144 B
    float* msall = (float*)(smem + 48128); // [1024]         4096 B
    // prologue scratch (dead before ks/pbf first use):
    float* wqt   = (float*)smem;           // [32][32] 4096 B, in ks region
    float* qtmp  = (float*)(smem + 29696); // [32][132] 16896 B, in pbf region

    const int t     = threadIdx.x;
    const int bid   = blockIdx.x;
    const int bh    = bid & 63;            // XCD = bid%8 = bh%8: strip-invariant
    const int strip = bid >> 6;
    const int b     = bh >> 3;
    const int h     = bh & 7;
    const int r0    = strip * 128;
    const int lane  = t & 63;
    const int w     = t >> 6;
    const int ln15  = lane & 15;
    const int lq    = lane >> 4;

    // ---- prologue: raw q tile (32j x 128l), WqT, full mask vector ----
    for (int idx = t; idx < 1024; idx += 256) {
        int j = idx >> 5, l4 = (idx & 31) * 4;
        *reinterpret_cast<float4*>(&qtmp[j * 132 + l4]) =
            *reinterpret_cast<const float4*>(&queries[(b * cD + h * cDK + j) * cL + r0 + l4]);
    }
    {
        int c = t >> 3, j4 = (t & 7) * 4;
        float4 wv = *reinterpret_cast<const float4*>(&Wq[(h * cDK + c) * cDK + j4]);
        wqt[(j4 + 0) * 32 + c] = wv.x; wqt[(j4 + 1) * 32 + c] = wv.y;
        wqt[(j4 + 2) * 32 + c] = wv.z; wqt[(j4 + 3) * 32 + c] = wv.w;
    }
    *reinterpret_cast<float4*>(&msall[t * 4]) =
        *reinterpret_cast<const float4*>(&mask[b * cL + t * 4]);
    __syncthreads();

    // ---- q projection (fp32 accumulate) -> fp16 qsb[r][c], rows 80 B ----
    // qsb (19456..29696) is disjoint from qtmp (29696..46592) and wqt
    // (0..4096): no barrier needed between rr iterations.
    #pragma unroll
    for (int rr = 0; rr < 2; ++rr) {
        const int r = rr * 64 + lane;
        float acc[8] = {0, 0, 0, 0, 0, 0, 0, 0};
        #pragma unroll
        for (int j = 0; j < 32; ++j) {
            float xv = qtmp[j * 132 + r];
            float4 w0 = *reinterpret_cast<const float4*>(&wqt[j * 32 + w * 8]);      // bcast
            float4 w1 = *reinterpret_cast<const float4*>(&wqt[j * 32 + w * 8 + 4]);
            acc[0] += w0.x * xv; acc[1] += w0.y * xv;
            acc[2] += w0.z * xv; acc[3] += w0.w * xv;
            acc[4] += w1.x * xv; acc[5] += w1.y * xv;
            acc[6] += w1.z * xv; acc[7] += w1.w * xv;
        }
        h8 hv;
        #pragma unroll
        for (int i = 0; i < 8; ++i) hv[i] = (f16)acc[i];
        *reinterpret_cast<h8*>(&qsb[r * 40 + w * 8]) = hv;
    }
    __syncthreads();   // scratch dead; qsb published

    const size_t kvbase = ((size_t)bh) * 32768;             // f16 units
    const int se = t >> 2, sb = (t & 3) * 8;                // K staging coords
    const int vc = t >> 3, veb = (t & 7) * 8;               // V staging coords

    // ---- stage tile 0 into buf 0 (first write to ks region) ----
    {
        h8 kh = *reinterpret_cast<const h8*>(&kp_h[kvbase + se * 32 + sb]);
        *reinterpret_cast<h8*>(&ks[se * 40 + sb]) = kh;
        h8 vv = *reinterpret_cast<const h8*>(&vp_h[kvbase + vc * 1024 + veb]);
        *reinterpret_cast<h8*>(&vsb[vc * 72 + veb]) = vv;
    }

    // ---- persistent B-frags: the wave's two q row-subtiles ----
    const h8 qf0 = *reinterpret_cast<const h8*>(&qsb[(w * 32 + ln15) * 40 + lq * 8]);
    const h8 qf1 = *reinterpret_cast<const h8*>(&qsb[(w * 32 + 16 + ln15) * 40 + lq * 8]);

    f4v o[2][2] = {{{0.f, 0.f, 0.f, 0.f}, {0.f, 0.f, 0.f, 0.f}},
                   {{0.f, 0.f, 0.f, 0.f}, {0.f, 0.f, 0.f, 0.f}}};
    float mo[2] = {-INFINITY, -INFINITY};
    float lr[2] = {0.f, 0.f};
    const int prow0 = (w * 32 + ln15) * 72;
    const int prow1 = (w * 32 + 16 + ln15) * 72;

    for (int et = 0; et < 16; ++et) {
        __syncthreads();        // tile et visible in buf pp
        const int pp = et & 1;
        const bool pre = (et < 15);
        h8 khp, vvp;
        if (pre) {              // early global loads for tile et+1
            const int e0n = (et + 1) * 64;
            khp = *reinterpret_cast<const h8*>(&kp_h[kvbase + (e0n + se) * 32 + sb]);
            vvp = *reinterpret_cast<const h8*>(&vp_h[kvbase + vc * 1024 + e0n + veb]);
        }

        // ---- S^T: D[e][r] = K[e][c] x Q^T[c][r]; ks frag reused for 2 rt ----
        f4v sA[4][2];
        #pragma unroll
        for (int es = 0; es < 4; ++es) {
            const h8 kf = *reinterpret_cast<const h8*>(
                &ks[pp * 2560 + (es * 16 + ln15) * 40 + lq * 8]);
            f4v z0 = {0.f, 0.f, 0.f, 0.f}, z1 = {0.f, 0.f, 0.f, 0.f};
            sA[es][0] = __builtin_amdgcn_mfma_f32_16x16x32_f16(kf, qf0, z0, 0, 0, 0);
            sA[es][1] = __builtin_amdgcn_mfma_f32_16x16x32_f16(kf, qf1, z1, 0, 0, 0);
        }

        // ---- softmax per rt: lane owns rows r = w*32 + rt*16 + ln15 ----
        float mn[2], al[2];
        #pragma unroll
        for (int rt = 0; rt < 2; ++rt) {
            float tm = fmaxf(
                fmaxf(fmaxf(sA[0][rt][0], sA[0][rt][1]), fmaxf(sA[0][rt][2], sA[0][rt][3])),
                fmaxf(fmaxf(fmaxf(sA[1][rt][0], sA[1][rt][1]), fmaxf(sA[1][rt][2], sA[1][rt][3])),
                fmaxf(fmaxf(fmaxf(sA[2][rt][0], sA[2][rt][1]), fmaxf(sA[2][rt][2], sA[2][rt][3])),
                      fmaxf(fmaxf(sA[3][rt][0], sA[3][rt][1]), fmaxf(sA[3][rt][2], sA[3][rt][3])))));
            tm = fmaxf(tm, __shfl_xor(tm, 16));
            tm = fmaxf(tm, __shfl_xor(tm, 32));
            mn[rt] = fmaxf(mo[rt], tm);
            al[rt] = __expf(mo[rt] - mn[rt]);     // first tile: exp(-inf) = 0
            mo[rt] = mn[rt];
            #pragma unroll
            for (int ch = 0; ch < 2; ++ch) {
                o[rt][ch][0] *= al[rt]; o[rt][ch][1] *= al[rt];
                o[rt][ch][2] *= al[rt]; o[rt][ch][3] *= al[rt];
            }
        }

        float ps[2] = {0.f, 0.f};
        #pragma unroll
        for (int es = 0; es < 4; ++es) {
            // broadcast read: all ln15 share this address
            float4 mk4 = *reinterpret_cast<const float4*>(&msall[et * 64 + es * 16 + lq * 4]);
            #pragma unroll
            for (int rt = 0; rt < 2; ++rt) {
                float p0 = __expf((sA[es][rt][0] - mn[rt]) * mk4.x) * mk4.x;
                float p1 = __expf((sA[es][rt][1] - mn[rt]) * mk4.y) * mk4.y;
                float p2 = __expf((sA[es][rt][2] - mn[rt]) * mk4.z) * mk4.z;
                float p3 = __expf((sA[es][rt][3] - mn[rt]) * mk4.w) * mk4.w;
                ps[rt] += (p0 + p1) + (p2 + p3);
                h4 pk; pk[0] = (f16)p0; pk[1] = (f16)p1; pk[2] = (f16)p2; pk[3] = (f16)p3;
                const int prow = rt ? prow1 : prow0;
                *reinterpret_cast<h4*>(&pbf[prow + es * 16 + lq * 4]) = pk;  // wave-private
            }
        }
        #pragma unroll
        for (int rt = 0; rt < 2; ++rt) {
            float p = ps[rt];
            p += __shfl_xor(p, 16);
            p += __shfl_xor(p, 32);
            lr[rt] = lr[rt] * al[rt] + p;
        }

        // ---- PV: o^T[c][r] += V[c][e] x P^T[e][r]; vs frags reused 2 rt ----
        #pragma unroll
        for (int ch = 0; ch < 2; ++ch) {
            h8 pf0 = *reinterpret_cast<const h8*>(&pbf[prow0 + ch * 32 + lq * 8]);
            h8 pf1 = *reinterpret_cast<const h8*>(&pbf[prow1 + ch * 32 + lq * 8]);
            h8 va0 = *reinterpret_cast<const h8*>(&vsb[pp * 2304 + ln15 * 72 + ch * 32 + lq * 8]);
            h8 va1 = *reinterpret_cast<const h8*>(&vsb[pp * 2304 + (16 + ln15) * 72 + ch * 32 + lq * 8]);
            o[0][0] = __builtin_amdgcn_mfma_f32_16x16x32_f16(va0, pf0, o[0][0], 0, 0, 0);
            o[0][1] = __builtin_amdgcn_mfma_f32_16x16x32_f16(va1, pf0, o[0][1], 0, 0, 0);
            o[1][0] = __builtin_amdgcn_mfma_f32_16x16x32_f16(va0, pf1, o[1][0], 0, 0, 0);
            o[1][1] = __builtin_amdgcn_mfma_f32_16x16x32_f16(va1, pf1, o[1][1], 0, 0, 0);
        }

        // ---- late LDS writes: publish tile et+1 into buf pp^1 ----
        if (pre) {
            *reinterpret_cast<h8*>(&ks[(pp ^ 1) * 2560 + se * 40 + sb]) = khp;
            *reinterpret_cast<h8*>(&vsb[(pp ^ 1) * 2304 + vc * 72 + veb]) = vvp;
        }
    }

    // ---- epilogue: val_h[b][l=r][h*32+c] = fp16(o / (l + eps)) ----
    #pragma unroll
    for (int rt = 0; rt < 2; ++rt) {
        const float linv = 1.0f / (lr[rt] + 1e-8f);
        const int r = r0 + w * 32 + rt * 16 + ln15;
        const size_t obase = ((size_t)(b * cL + r)) * cD + h * cDK;
        h4 q0, q1;
        #pragma unroll
        for (int i = 0; i < 4; ++i) {
            q0[i] = (f16)(o[rt][0][i] * linv);
            q1[i] = (f16)(o[rt][1][i] * linv);
        }
        *reinterpret_cast<h4*>(&val_h[obase + lq * 4])      = q0;
        *reinterpret_cast<h4*>(&val_h[obase + 16 + lq * 4]) = q1;
    }
}

// ---------------------------------------------------------------------------
// Kernel 3: out[b][l][i] = mask[b][l] * (sum_j Wp[i][j]*val[b][l][j] + bp[i])
// fp16 MFMA. grid 512 = (b:8, lt:16 of 64 l, it:4 of 64 i), block 256.
// ---------------------------------------------------------------------------
__global__ __launch_bounds__(256, 2) void outproj_kernel(
    const f16* __restrict__ val_h, const float* __restrict__ Wp,
    const float* __restrict__ bp, const float* __restrict__ mask,
    float* __restrict__ out)
{
    __shared__ __align__(16) f16 vt[64 * 264];    // [64 l][264 j-pad] rows 528 B
    __shared__ __align__(16) f16 wpb[64 * 264];   // [64 i][264 j-pad]
    __shared__ float mrow[64];

    const int t    = threadIdx.x;
    const int bid  = blockIdx.x;
    const int it   = bid & 3;
    const int lt   = (bid >> 2) & 15;
    const int b    = bid >> 6;
    const int l0   = lt * 64, i0 = it * 64;
    const int lane = t & 63, w = t >> 6, ln15 = lane & 15, lq = lane >> 4;

    {   // stage val tile; row = t&63 fast -> conflict-free LDS writes
        int row = t & 63, seg = (t >> 6) * 64;
        const f16* src = &val_h[((size_t)(b * cL + l0 + row)) * cD + seg];
        #pragma unroll
        for (int k = 0; k < 8; ++k)
            *reinterpret_cast<h8*>(&vt[row * 264 + seg + k * 8]) =
                *reinterpret_cast<const h8*>(src + k * 8);
    }
    {   // stage Wp tile (fp32 -> fp16)
        int row = t & 63, seg = (t >> 6) * 64;
        const float* src = &Wp[((size_t)(i0 + row)) * cD + seg];
        #pragma unroll
        for (int k = 0; k < 8; ++k) {
            float4 f0 = *reinterpret_cast<const float4*>(src + k * 8);
            float4 f1 = *reinterpret_cast<const float4*>(src + k * 8 + 4);
            h8 hv;
            hv[0] = (f16)f0.x; hv[1] = (f16)f0.y; hv[2] = (f16)f0.z; hv[3] = (f16)f0.w;
            hv[4] = (f16)f1.x; hv[5] = (f16)f1.y; hv[6] = (f16)f1.z; hv[7] = (f16)f1.w;
            *reinterpret_cast<h8*>(&wpb[row * 264 + seg + k * 8]) = hv;
        }
    }
    if (t < 64) mrow[t] = mask[b * cL + l0 + t];
    __syncthreads();

    f4v acc[4] = {{0.f, 0.f, 0.f, 0.f}, {0.f, 0.f, 0.f, 0.f},
                  {0.f, 0.f, 0.f, 0.f}, {0.f, 0.f, 0.f, 0.f}};
    #pragma unroll
    for (int kc = 0; kc < 8; ++kc) {
        h8 aA = *reinterpret_cast<const h8*>(&vt[(w * 16 + ln15) * 264 + kc * 32 + lq * 8]);
        #pragma unroll
        for (int ti = 0; ti < 4; ++ti) {
            h8 bB = *reinterpret_cast<const h8*>(&wpb[(ti * 16 + ln15) * 264 + kc * 32 + lq * 8]);
            acc[ti] = __builtin_amdgcn_mfma_f32_16x16x32_f16(aA, bB, acc[ti], 0, 0, 0);
        }
    }

    float mk[4];
    #pragma unroll
    for (int rg = 0; rg < 4; ++rg) mk[rg] = mrow[w * 16 + lq * 4 + rg];
    #pragma unroll
    for (int ti = 0; ti < 4; ++ti) {
        float bpv = bp[i0 + ti * 16 + ln15];
        #pragma unroll
        for (int rg = 0; rg < 4; ++rg) {
            int l = l0 + w * 16 + lq * 4 + rg;
            out[((size_t)(b * cL + l)) * cD + i0 + ti * 16 + ln15] =
                (acc[ti][rg] + bpv) * mk[rg];
        }
    }
}

// ---------------------------------------------------------------------------
extern "C" void kernel_launch(void* const* d_in, const int* in_sizes, int n_in,
                              void* d_out, int out_size, void* d_ws, size_t ws_size,
                              hipStream_t stream) {
    const float* queries = (const float*)d_in[0];
    const float* keys    = (const float*)d_in[1];
    const float* values  = (const float*)d_in[2];
    const float* mask    = (const float*)d_in[3];
    const float* Wq      = (const float*)d_in[4];
    const float* Wk      = (const float*)d_in[5];
    const float* Wv      = (const float*)d_in[6];
    const float* Wp      = (const float*)d_in[7];
    const float* bp      = (const float*)d_in[8];
    float* out = (float*)d_out;

    // ws: kp_h 4MB | vp_h 4MB | val_h 4MB  (12 MB)
    char* wsb = (char*)d_ws;
    f16* kp_h  = (f16*)(wsb);
    f16* vp_h  = (f16*)(wsb + (4u << 20));
    f16* val_h = (f16*)(wsb + (8u << 20));

    proj_kv_kernel<<<dim3(1024), dim3(256), 0, stream>>>(keys, values, mask, Wk, Wv,
                                                         kp_h, vp_h);
    attn_kernel<<<dim3(512), dim3(256), 0, stream>>>(queries, mask, Wq,
                                                     kp_h, vp_h, val_h);
    outproj_kernel<<<dim3(512), dim3(256), 0, stream>>>(val_h, Wp, bp, mask, out);
}

// Round 7
// 127.328 us; speedup vs baseline: 1.0537x; 1.0537x over previous
//
#include <hip/hip_runtime.h>
#include <math.h>

// MHAttention: BS=8, D=256, L=1024, H=8, DK=32
// Round 7: (1) proj_qkv: all three projections via MFMA with ZERO LDS --
// A-frag = W rows (contiguous global), B-frag = X columns (strided dword
// gather, 64B segments). Q written in [r][c] B-frag layout so attn loads
// its persistent q-frags straight from global (whole q prologue deleted).
// (2) attn back to 64-row blocks (R4 beat R6's 128-row), msall dropped
// (per-tile global mask reads), LDS 28 KB -> 5 blocks/CU (20 waves),
// p = mk*exp(s-mn) (inner mask-mul provably redundant), lr shuffle-reduce
// deferred to epilogue. (3) outproj unchanged.

constexpr int cD  = 256;
constexpr int cL  = 1024;
constexpr int cH  = 8;
constexpr int cDK = 32;

typedef _Float16 f16;
typedef __attribute__((ext_vector_type(8))) _Float16 h8;   // 8 f16 = 4 VGPRs
typedef __attribute__((ext_vector_type(4))) _Float16 h4;   // 8 B
typedef __attribute__((ext_vector_type(4))) float f4v;     // MFMA C/D

// ---------------------------------------------------------------------------
// Kernel 1: Q,K,V projections via MFMA. grid 1024 = (bh:64, lt:16 of 64 l),
// block 256; wave w owns l-subtile l0 + w*16 + ln15.
// D[c][l] = sum_j W[c][j] * X[j][l]  (A = W fp16 frag, B = X^T column frag)
// Outputs: qp[bh][r][c] (B-frag layout for attn), kp[bh][e][c] masked,
// vp[bh][c][e].
// ---------------------------------------------------------------------------
__global__ __launch_bounds__(256, 4) void proj_qkv_kernel(
    const float* __restrict__ queries, const float* __restrict__ keys,
    const float* __restrict__ values, const float* __restrict__ mask,
    const float* __restrict__ Wq, const float* __restrict__ Wk,
    const float* __restrict__ Wv, f16* __restrict__ qp_h,
    f16* __restrict__ kp_h, f16* __restrict__ vp_h)
{
    const int t    = threadIdx.x;
    const int bid  = blockIdx.x;
    const int lt   = bid & 15;
    const int bh   = bid >> 4;
    const int h    = bh & 7;
    const int b    = bh >> 3;
    const int l0   = lt * 64;
    const int lane = t & 63, w = t >> 6, ln15 = lane & 15, lq = lane >> 4;
    const int l    = l0 + w * 16 + ln15;     // this lane's l (MFMA n-index)

    const float mk = mask[b * cL + l];
    const size_t xbase = ((size_t)(b * cD + h * cDK)) * cL + l;   // + j*cL
    const int    wbase = h * cDK * cDK + lq * 8;                  // + c*cDK

    const float* Xs[3] = {queries, keys, values};
    const float* Ws[3] = {Wq, Wk, Wv};
    f4v d0[3], d1[3];

    #pragma unroll
    for (int m = 0; m < 3; ++m) {
        const float* __restrict__ X = Xs[m];
        const float* __restrict__ W = Ws[m];
        h8 bx, a0, a1;
        #pragma unroll
        for (int i = 0; i < 8; ++i)
            bx[i] = (f16)X[xbase + (size_t)(lq * 8 + i) * cL];
        #pragma unroll
        for (int i = 0; i < 8; ++i) {
            a0[i] = (f16)W[wbase + ln15 * cDK + i];
            a1[i] = (f16)W[wbase + (16 + ln15) * cDK + i];
        }
        f4v z = {0.f, 0.f, 0.f, 0.f};
        d0[m] = __builtin_amdgcn_mfma_f32_16x16x32_f16(a0, bx, z, 0, 0, 0);
        d1[m] = __builtin_amdgcn_mfma_f32_16x16x32_f16(a1, bx, z, 0, 0, 0);
    }

    // ---- Q: [r=l][c], fp16 ----
    {
        const size_t qb = ((size_t)bh * cL + l) * cDK;
        h4 o0, o1;
        #pragma unroll
        for (int i = 0; i < 4; ++i) { o0[i] = (f16)d0[0][i]; o1[i] = (f16)d1[0][i]; }
        *reinterpret_cast<h4*>(&qp_h[qb + lq * 4])      = o0;
        *reinterpret_cast<h4*>(&qp_h[qb + 16 + lq * 4]) = o1;
    }
    // ---- K: [e=l][c], masked ----
    {
        const size_t kb = ((size_t)bh * cL + l) * cDK;
        h4 o0, o1;
        #pragma unroll
        for (int i = 0; i < 4; ++i) {
            o0[i] = (f16)(d0[1][i] * mk);
            o1[i] = (f16)(d1[1][i] * mk);
        }
        *reinterpret_cast<h4*>(&kp_h[kb + lq * 4])      = o0;
        *reinterpret_cast<h4*>(&kp_h[kb + 16 + lq * 4]) = o1;
    }
    // ---- V: [c][e=l] ----
    {
        const size_t vb = (size_t)bh * cDK * cL + l;
        #pragma unroll
        for (int i = 0; i < 4; ++i) {
            vp_h[vb + (size_t)(lq * 4 + i) * cL]      = (f16)d0[2][i];
            vp_h[vb + (size_t)(16 + lq * 4 + i) * cL] = (f16)d1[2][i];
        }
    }
}

// ---------------------------------------------------------------------------
// Kernel 2: fused attention, fp16 MFMA. Block = (b, h, 64-row strip), 4
// waves; wave w owns rows r = w*16 + ln15 (one row per lane end-to-end).
// grid 1024 = (b:8, h:8, strip:16); consecutive bids = strips of one (b,h)
// -> same XCD reuses that (b,h)'s K/V in L2. 28 KB LDS -> 5 blocks/CU.
// ---------------------------------------------------------------------------
__global__ __launch_bounds__(256, 5) void attn_kernel(
    const float* __restrict__ mask, const f16* __restrict__ qp_h,
    const f16* __restrict__ kp_h, const f16* __restrict__ vp_h,
    f16* __restrict__ val_h)
{
    __shared__ __align__(16) char smem[28672];
    f16* ks  = (f16*)smem;             // [2][64e][40]  10240 B, rows 80 B
    f16* vsb = (f16*)(smem + 10240);   // [2][32c][72]   9216 B, rows 144 B
    f16* pbf = (f16*)(smem + 19456);   // [64r][72]      9216 B, rows 144 B

    const int t     = threadIdx.x;
    const int bid   = blockIdx.x;
    const int strip = bid & 15;
    const int bh    = bid >> 4;
    const int b     = bh >> 3;
    const int r0    = strip * 64;
    const int lane  = t & 63;
    const int w     = t >> 6;
    const int ln15  = lane & 15;
    const int lq    = lane >> 4;

    const size_t kvbase = ((size_t)bh) * 32768;             // f16 units
    const int se = t >> 2, sb = (t & 3) * 8;                // K staging coords
    const int vc = t >> 3, veb = (t & 7) * 8;               // V staging coords

    // ---- persistent B-frag: this lane's q row, straight from global ----
    const h8 qf = *reinterpret_cast<const h8*>(
        &qp_h[((size_t)bh * cL + r0 + w * 16 + ln15) * cDK + lq * 8]);

    // ---- stage tile 0 into buf 0 ----
    {
        h8 kh = *reinterpret_cast<const h8*>(&kp_h[kvbase + se * 32 + sb]);
        *reinterpret_cast<h8*>(&ks[se * 40 + sb]) = kh;
        h8 vv = *reinterpret_cast<const h8*>(&vp_h[kvbase + vc * 1024 + veb]);
        *reinterpret_cast<h8*>(&vsb[vc * 72 + veb]) = vv;
    }

    f4v o0 = {0.f, 0.f, 0.f, 0.f}, o1 = {0.f, 0.f, 0.f, 0.f};
    float mo = -INFINITY, lrp = 0.f;   // lrp: per-lane partial (16 e-cols)
    const int prow  = (w * 16 + ln15) * 72;
    const int vsoff = ln15 * 72 + lq * 8;

    for (int et = 0; et < 16; ++et) {
        __syncthreads();        // tile et visible in buf pp
        const int pp = et & 1;
        const bool pre = (et < 15);
        h8 khp, vvp;
        if (pre) {              // early global loads for tile et+1
            const int e0n = (et + 1) * 64;
            khp = *reinterpret_cast<const h8*>(&kp_h[kvbase + (e0n + se) * 32 + sb]);
            vvp = *reinterpret_cast<const h8*>(&vp_h[kvbase + vc * 1024 + e0n + veb]);
        }
        // mask for this tile: broadcast global reads (L1-hot), prefetched
        float4 mk4[4];
        #pragma unroll
        for (int es = 0; es < 4; ++es)
            mk4[es] = *reinterpret_cast<const float4*>(
                &mask[b * cL + et * 64 + es * 16 + lq * 4]);

        // ---- S^T tiles: D[e][r] = K[e][c] x Q^T[c][r] ----
        f4v sA[4];
        #pragma unroll
        for (int es = 0; es < 4; ++es) {
            const h8 kf = *reinterpret_cast<const h8*>(
                &ks[pp * 2560 + (es * 16 + ln15) * 40 + lq * 8]);
            f4v z = {0.f, 0.f, 0.f, 0.f};
            sA[es] = __builtin_amdgcn_mfma_f32_16x16x32_f16(kf, qf, z, 0, 0, 0);
        }

        // ---- softmax: lane owns row r = w*16+ln15 (scalar stats) ----
        float tm = fmaxf(fmaxf(fmaxf(sA[0][0], sA[0][1]), fmaxf(sA[0][2], sA[0][3])),
                   fmaxf(fmaxf(fmaxf(sA[1][0], sA[1][1]), fmaxf(sA[1][2], sA[1][3])),
                   fmaxf(fmaxf(fmaxf(sA[2][0], sA[2][1]), fmaxf(sA[2][2], sA[2][3])),
                         fmaxf(fmaxf(sA[3][0], sA[3][1]), fmaxf(sA[3][2], sA[3][3])))));
        tm = fmaxf(tm, __shfl_xor(tm, 16));
        tm = fmaxf(tm, __shfl_xor(tm, 32));
        const float mn = fmaxf(mo, tm);
        const float al = __expf(mo - mn);     // first tile: exp(-inf) = 0
        mo = mn;
        o0[0] *= al; o0[1] *= al; o0[2] *= al; o0[3] *= al;
        o1[0] *= al; o1[1] *= al; o1[2] *= al; o1[3] *= al;

        float ps = 0.f;
        #pragma unroll
        for (int es = 0; es < 4; ++es) {
            // p = mask * exp(s - mn): inner mask-mul redundant (masked s=0<=mn)
            float p0 = mk4[es].x * __expf(sA[es][0] - mn);
            float p1 = mk4[es].y * __expf(sA[es][1] - mn);
            float p2 = mk4[es].z * __expf(sA[es][2] - mn);
            float p3 = mk4[es].w * __expf(sA[es][3] - mn);
            ps += (p0 + p1) + (p2 + p3);
            h4 pk; pk[0] = (f16)p0; pk[1] = (f16)p1; pk[2] = (f16)p2; pk[3] = (f16)p3;
            *reinterpret_cast<h4*>(&pbf[prow + es * 16 + lq * 4]) = pk;  // wave-private
        }
        lrp = lrp * al + ps;   // shuffle-reduce deferred to epilogue

        // ---- PV: o^T[c][r] += V[c][e] x P^T[e][r] (same-wave, no barrier) ----
        #pragma unroll
        for (int ch = 0; ch < 2; ++ch) {
            h8 pf  = *reinterpret_cast<const h8*>(&pbf[prow + ch * 32 + lq * 8]);
            h8 va0 = *reinterpret_cast<const h8*>(&vsb[pp * 2304 + vsoff + ch * 32]);
            h8 va1 = *reinterpret_cast<const h8*>(&vsb[pp * 2304 + vsoff + ch * 32 + 1152]);
            o0 = __builtin_amdgcn_mfma_f32_16x16x32_f16(va0, pf, o0, 0, 0, 0);
            o1 = __builtin_amdgcn_mfma_f32_16x16x32_f16(va1, pf, o1, 0, 0, 0);
        }

        // ---- late LDS writes: publish tile et+1 into buf pp^1 ----
        if (pre) {
            *reinterpret_cast<h8*>(&ks[(pp ^ 1) * 2560 + se * 40 + sb]) = khp;
            *reinterpret_cast<h8*>(&vsb[(pp ^ 1) * 2304 + vc * 72 + veb]) = vvp;
        }
    }

    // ---- epilogue: complete row-sum, divide, store ----
    {
        float lr = lrp;
        lr += __shfl_xor(lr, 16);
        lr += __shfl_xor(lr, 32);
        const float linv = 1.0f / (lr + 1e-8f);
        const int h = bh & 7;
        const size_t obase = ((size_t)(b * cL + r0 + w * 16 + ln15)) * cD + h * cDK;
        h4 q0, q1;
        #pragma unroll
        for (int i = 0; i < 4; ++i) {
            q0[i] = (f16)(o0[i] * linv);
            q1[i] = (f16)(o1[i] * linv);
        }
        *reinterpret_cast<h4*>(&val_h[obase + lq * 4])      = q0;
        *reinterpret_cast<h4*>(&val_h[obase + 16 + lq * 4]) = q1;
    }
}

// ---------------------------------------------------------------------------
// Kernel 3: out[b][l][i] = mask[b][l] * (sum_j Wp[i][j]*val[b][l][j] + bp[i])
// fp16 MFMA. grid 512 = (b:8, lt:16 of 64 l, it:4 of 64 i), block 256.
// ---------------------------------------------------------------------------
__global__ __launch_bounds__(256, 2) void outproj_kernel(
    const f16* __restrict__ val_h, const float* __restrict__ Wp,
    const float* __restrict__ bp, const float* __restrict__ mask,
    float* __restrict__ out)
{
    __shared__ __align__(16) f16 vt[64 * 264];    // [64 l][264 j-pad] rows 528 B
    __shared__ __align__(16) f16 wpb[64 * 264];   // [64 i][264 j-pad]
    __shared__ float mrow[64];

    const int t    = threadIdx.x;
    const int bid  = blockIdx.x;
    const int it   = bid & 3;
    const int lt   = (bid >> 2) & 15;
    const int b    = bid >> 6;
    const int l0   = lt * 64, i0 = it * 64;
    const int lane = t & 63, w = t >> 6, ln15 = lane & 15, lq = lane >> 4;

    {   // stage val tile; row = t&63 fast -> conflict-free LDS writes
        int row = t & 63, seg = (t >> 6) * 64;
        const f16* src = &val_h[((size_t)(b * cL + l0 + row)) * cD + seg];
        #pragma unroll
        for (int k = 0; k < 8; ++k)
            *reinterpret_cast<h8*>(&vt[row * 264 + seg + k * 8]) =
                *reinterpret_cast<const h8*>(src + k * 8);
    }
    {   // stage Wp tile (fp32 -> fp16)
        int row = t & 63, seg = (t >> 6) * 64;
        const float* src = &Wp[((size_t)(i0 + row)) * cD + seg];
        #pragma unroll
        for (int k = 0; k < 8; ++k) {
            float4 f0 = *reinterpret_cast<const float4*>(src + k * 8);
            float4 f1 = *reinterpret_cast<const float4*>(src + k * 8 + 4);
            h8 hv;
            hv[0] = (f16)f0.x; hv[1] = (f16)f0.y; hv[2] = (f16)f0.z; hv[3] = (f16)f0.w;
            hv[4] = (f16)f1.x; hv[5] = (f16)f1.y; hv[6] = (f16)f1.z; hv[7] = (f16)f1.w;
            *reinterpret_cast<h8*>(&wpb[row * 264 + seg + k * 8]) = hv;
        }
    }
    if (t < 64) mrow[t] = mask[b * cL + l0 + t];
    __syncthreads();

    f4v acc[4] = {{0.f, 0.f, 0.f, 0.f}, {0.f, 0.f, 0.f, 0.f},
                  {0.f, 0.f, 0.f, 0.f}, {0.f, 0.f, 0.f, 0.f}};
    #pragma unroll
    for (int kc = 0; kc < 8; ++kc) {
        h8 aA = *reinterpret_cast<const h8*>(&vt[(w * 16 + ln15) * 264 + kc * 32 + lq * 8]);
        #pragma unroll
        for (int ti = 0; ti < 4; ++ti) {
            h8 bB = *reinterpret_cast<const h8*>(&wpb[(ti * 16 + ln15) * 264 + kc * 32 + lq * 8]);
            acc[ti] = __builtin_amdgcn_mfma_f32_16x16x32_f16(aA, bB, acc[ti], 0, 0, 0);
        }
    }

    float mk[4];
    #pragma unroll
    for (int rg = 0; rg < 4; ++rg) mk[rg] = mrow[w * 16 + lq * 4 + rg];
    #pragma unroll
    for (int ti = 0; ti < 4; ++ti) {
        float bpv = bp[i0 + ti * 16 + ln15];
        #pragma unroll
        for (int rg = 0; rg < 4; ++rg) {
            int l = l0 + w * 16 + lq * 4 + rg;
            out[((size_t)(b * cL + l)) * cD + i0 + ti * 16 + ln15] =
                (acc[ti][rg] + bpv) * mk[rg];
        }
    }
}

// ---------------------------------------------------------------------------
extern "C" void kernel_launch(void* const* d_in, const int* in_sizes, int n_in,
                              void* d_out, int out_size, void* d_ws, size_t ws_size,
                              hipStream_t stream) {
    const float* queries = (const float*)d_in[0];
    const float* keys    = (const float*)d_in[1];
    const float* values  = (const float*)d_in[2];
    const float* mask    = (const float*)d_in[3];
    const float* Wq      = (const float*)d_in[4];
    const float* Wk      = (const float*)d_in[5];
    const float* Wv      = (const float*)d_in[6];
    const float* Wp      = (const float*)d_in[7];
    const float* bp      = (const float*)d_in[8];
    float* out = (float*)d_out;

    // ws: qp 4MB | kp 4MB | vp 4MB | val 4MB  (16 MB)
    char* wsb = (char*)d_ws;
    f16* qp_h  = (f16*)(wsb);
    f16* kp_h  = (f16*)(wsb + (4u << 20));
    f16* vp_h  = (f16*)(wsb + (8u << 20));
    f16* val_h = (f16*)(wsb + (12u << 20));

    proj_qkv_kernel<<<dim3(1024), dim3(256), 0, stream>>>(
        queries, keys, values, mask, Wq, Wk, Wv, qp_h, kp_h, vp_h);
    attn_kernel<<<dim3(1024), dim3(256), 0, stream>>>(
        mask, qp_h, kp_h, vp_h, val_h);
    outproj_kernel<<<dim3(512), dim3(256), 0, stream>>>(val_h, Wp, bp, mask, out);
}